// Round 2
// baseline (4597.153 us; speedup 1.0000x reference)
//
#include <hip/hip_runtime.h>
#include <hip/hip_bf16.h>
#include <math.h>

#define V_NODES 50000
#define E_EDGES 25000
#define NNZ     600000
#define S_SUB   8
#define K_SUB   16
#define DD      128      // S*K
#define NUM_STEP 4
#define EPSF    1e-10f

// stats layout per side (side = 2*step + {0:Y,1:X}), stride 2177 floats:
// [0] entropy sum; [1..128] colsum; [129..2176] gram (s*256 + i*16 + j)
#define STATS_STRIDE 2177

// ---------------- softmax over groups of 16 (gumbel-softmax X0) -------------
__global__ void softmax16_kernel(const float* __restrict__ emb,
                                 const float* __restrict__ gum,
                                 float* __restrict__ X) {
    int i = blockIdx.x * blockDim.x + threadIdx.x;
    if (i >= V_NODES * DD) return;
    float x = emb[i] + gum[i];          // TAU = 1.0
    float m = x;
    #pragma unroll
    for (int off = 1; off < 16; off <<= 1) m = fmaxf(m, __shfl_xor(m, off, 16));
    float e = expf(x - m);
    float s = e;
    #pragma unroll
    for (int off = 1; off < 16; off <<= 1) s += __shfl_xor(s, off, 16);
    X[i] = e / s;
}

// ---------------- int histogram of segment counts ---------------------------
__global__ void hist_kernel(const int* __restrict__ Vi, const int* __restrict__ Ei,
                            int* __restrict__ cntV, int* __restrict__ cntE) {
    int n = blockIdx.x * blockDim.x + threadIdx.x;
    if (n >= NNZ) return;
    atomicAdd(&cntV[Vi[n]], 1);
    atomicAdd(&cntE[Ei[n]], 1);
}

// ---------------- single-block exclusive scan (N <= 50000) ------------------
__global__ void scan_kernel(const int* __restrict__ cnt, int N,
                            int* __restrict__ off, int* __restrict__ cur) {
    __shared__ int tmp[1024];
    __shared__ int sh_carry;
    int t = threadIdx.x;
    if (t == 0) sh_carry = 0;
    __syncthreads();
    for (int base = 0; base < N; base += 1024) {
        int c = sh_carry;
        int i = base + t;
        int v = (i < N) ? cnt[i] : 0;
        tmp[t] = v; __syncthreads();
        for (int st = 1; st < 1024; st <<= 1) {
            int add = (t >= st) ? tmp[t - st] : 0;
            __syncthreads();
            tmp[t] += add;
            __syncthreads();
        }
        if (i < N) { int e = c + tmp[t] - v; off[i] = e; cur[i] = e; }
        __syncthreads();
        if (t == 1023) sh_carry = c + tmp[1023];
        __syncthreads();
    }
}

// ---------------- fill CSR adjacency lists ----------------------------------
// listE[slot for edge e] = source node v ;  listV[slot for node v] = source edge e
__global__ void fill_kernel(const int* __restrict__ Vi, const int* __restrict__ Ei,
                            int* __restrict__ curE, int* __restrict__ curV,
                            int* __restrict__ listE, int* __restrict__ listV) {
    int n = blockIdx.x * blockDim.x + threadIdx.x;
    if (n >= NNZ) return;
    int v = Vi[n], e = Ei[n];
    listE[atomicAdd(&curE[e], 1)] = v;
    listV[atomicAdd(&curV[v], 1)] = e;
}

// ------- segmented mean (gather form) fused with entropy/colsum/gram --------
// 256 threads = 2 rows per block iteration; 128 threads own one column each.
__global__ void gather_mean_stats(const float* __restrict__ src,
                                  float* __restrict__ dst,
                                  const int* __restrict__ list,
                                  const int* __restrict__ off,
                                  const int* __restrict__ cnt,
                                  int N, float* __restrict__ stats) {
    int t = threadIdx.x;
    int r0 = t >> 7;         // row-in-pair (0/1)
    int d = t & 127;         // column
    int s = d >> 4;          // subspace
    int i = d & 15;          // index within subspace

    float ent = 0.f, col = 0.f;
    float gram[16];
    #pragma unroll
    for (int j = 0; j < 16; ++j) gram[j] = 0.f;

    for (int row = blockIdx.x * 2 + r0; row < N; row += gridDim.x * 2) {
        int deg = cnt[row];
        int o = off[row];
        float y = 0.f;
        for (int k = 0; k < deg; ++k)
            y += src[(size_t)list[o + k] * DD + d];
        y /= fmaxf((float)deg, 1.0f);
        dst[(size_t)row * DD + d] = y;
        ent -= y * logf(y + EPSF);
        col += y;
        #pragma unroll
        for (int j = 0; j < 16; ++j) {
            float yj = __shfl(y, j, 16);   // broadcast within 16-lane group
            gram[j] += y * yj;
        }
    }

    __shared__ float red[256];
    red[t] = ent; __syncthreads();
    for (int st = 128; st > 0; st >>= 1) {
        if (t < st) red[t] += red[t + st];
        __syncthreads();
    }
    if (t == 0) atomicAdd(&stats[0], red[0]);
    __syncthreads();
    red[t] = col; __syncthreads();
    if (t < 128) atomicAdd(&stats[1 + d], red[t] + red[t + 128]);
    __syncthreads();
    for (int j = 0; j < 16; ++j) {
        red[t] = gram[j]; __syncthreads();
        if (t < 128) atomicAdd(&stats[129 + s * 256 + i * 16 + j], red[t] + red[t + 128]);
        __syncthreads();
    }
}

// ---------------- final loss from the 8 stats blocks ------------------------
__global__ void loss_kernel(const float* __restrict__ stats, float* __restrict__ out) {
    int t = threadIdx.x;
    float acc_l = 0.f, acc_g = 0.f;

    if (t < 8) {
        float N = (t & 1) ? (float)V_NODES : (float)E_EDGES;
        acc_l = stats[t * STATS_STRIDE] / (N * (float)S_SUB);
    }

    for (int u = t; u < 8 * 128; u += blockDim.x) {
        int side = u >> 7, d = u & 127;
        float N = (side & 1) ? (float)V_NODES : (float)E_EDGES;
        float p = stats[side * STATS_STRIDE + 1 + d] / N;
        acc_g += p * logf(p + EPSF) / (float)S_SUB;
    }

    for (int u = t; u < 8 * 8 * 16; u += blockDim.x) {
        int side = u >> 7;
        int s = (u >> 4) & 7;
        int i = u & 15;
        const float* G = stats + side * STATS_STRIDE + 129 + s * 256;
        float nii = sqrtf(G[i * 16 + i]);
        float C[16];
        float m = -INFINITY;
        #pragma unroll
        for (int j = 0; j < 16; ++j) {
            float njj = sqrtf(G[j * 16 + j]);
            float c = G[i * 16 + j] / fmaxf(nii * njj, EPSF);
            C[j] = c;
            m = fmaxf(m, c);
        }
        float sum = 0.f;
        #pragma unroll
        for (int j = 0; j < 16; ++j) sum += expf(C[j] - m);
        float lse = logf(sum) + m;
        acc_g += (lse - C[i]) / (float)(S_SUB * K_SUB);
    }

    __shared__ float redl[256], redg[256];
    redl[t] = acc_l; redg[t] = acc_g; __syncthreads();
    for (int st = 128; st > 0; st >>= 1) {
        if (t < st) { redl[t] += redl[t + st]; redg[t] += redg[t + st]; }
        __syncthreads();
    }
    if (t == 0) { out[0] = redl[0]; out[1] = redg[0]; }
}

extern "C" void kernel_launch(void* const* d_in, const int* in_sizes, int n_in,
                              void* d_out, int out_size, void* d_ws, size_t ws_size,
                              hipStream_t stream) {
    const float* emb = (const float*)d_in[0];
    const float* gum = (const float*)d_in[1];
    const int*   Vi  = (const int*)d_in[2];
    const int*   Ei  = (const int*)d_in[3];
    float* out = (float*)d_out;

    char* ws = (char*)d_ws;
    size_t off = 0;
    float* X = (float*)(ws + off);      off += (size_t)V_NODES * DD * 4;   // 25.6 MB
    float* Y = (float*)(ws + off);      off += (size_t)E_EDGES * DD * 4;   // 12.8 MB
    int* listE = (int*)(ws + off);      off += (size_t)NNZ * 4;            // 2.4 MB
    int* listV = (int*)(ws + off);      off += (size_t)NNZ * 4;            // 2.4 MB
    int* cntE  = (int*)(ws + off);      off += (size_t)E_EDGES * 4;
    int* cntV  = (int*)(ws + off);      off += (size_t)V_NODES * 4;
    int* offE  = (int*)(ws + off);      off += (size_t)E_EDGES * 4;
    int* offV  = (int*)(ws + off);      off += (size_t)V_NODES * 4;
    int* curE  = (int*)(ws + off);      off += (size_t)E_EDGES * 4;
    int* curV  = (int*)(ws + off);      off += (size_t)V_NODES * 4;
    float* stats = (float*)(ws + off);  off += (size_t)8 * STATS_STRIDE * 4;

    // zero counts + stats every launch (deterministic state)
    hipMemsetAsync(cntE, 0, ((size_t)E_EDGES + V_NODES) * 4, stream);
    hipMemsetAsync(stats, 0, (size_t)8 * STATS_STRIDE * 4, stream);

    softmax16_kernel<<<(V_NODES * DD + 255) / 256, 256, 0, stream>>>(emb, gum, X);
    hist_kernel<<<(NNZ + 255) / 256, 256, 0, stream>>>(Vi, Ei, cntV, cntE);
    scan_kernel<<<1, 1024, 0, stream>>>(cntE, E_EDGES, offE, curE);
    scan_kernel<<<1, 1024, 0, stream>>>(cntV, V_NODES, offV, curV);
    fill_kernel<<<(NNZ + 255) / 256, 256, 0, stream>>>(Vi, Ei, curE, curV, listE, listV);

    const int GB = 1024;   // grid for gather kernels
    for (int step = 0; step < NUM_STEP; ++step) {
        // Y = scatter_mean(X[Vi], Ei)  ==  per-edge mean over listE
        gather_mean_stats<<<GB, 256, 0, stream>>>(X, Y, listE, offE, cntE, E_EDGES,
                                                  stats + (2 * step) * STATS_STRIDE);
        // X = scatter_mean(Y[Ei], Vi)  ==  per-node mean over listV
        gather_mean_stats<<<GB, 256, 0, stream>>>(Y, X, listV, offV, cntV, V_NODES,
                                                  stats + (2 * step + 1) * STATS_STRIDE);
    }

    loss_kernel<<<1, 256, 0, stream>>>(stats, out);
}

// Round 3
// 1618.244 us; speedup vs baseline: 2.8408x; 2.8408x over previous
//
#include <hip/hip_runtime.h>
#include <hip/hip_bf16.h>
#include <math.h>

#define V_NODES 50000
#define E_EDGES 25000
#define NNZ     600000
#define S_SUB   8
#define K_SUB   16
#define DD      128      // S*K
#define NUM_STEP 4
#define EPSF    1e-10f

// stats layout per side (side = 2*step + {0:Y,1:X}), stride 2177 floats:
// [0] entropy sum; [1..128] colsum; [129..2176] gram (s*256 + i*16 + j)
#define STATS_STRIDE 2177

// ---------------- softmax over groups of 16 (gumbel-softmax X0) -------------
__global__ void softmax16_kernel(const float* __restrict__ emb,
                                 const float* __restrict__ gum,
                                 float* __restrict__ X) {
    int i = blockIdx.x * blockDim.x + threadIdx.x;
    if (i >= V_NODES * DD) return;
    float x = emb[i] + gum[i];          // TAU = 1.0
    float m = x;
    #pragma unroll
    for (int off = 1; off < 16; off <<= 1) m = fmaxf(m, __shfl_xor(m, off, 16));
    float e = expf(x - m);
    float s = e;
    #pragma unroll
    for (int off = 1; off < 16; off <<= 1) s += __shfl_xor(s, off, 16);
    X[i] = e / s;
}

// ---------------- int histogram of segment counts ---------------------------
__global__ void hist_kernel(const int* __restrict__ Vi, const int* __restrict__ Ei,
                            int* __restrict__ cntV, int* __restrict__ cntE) {
    int n = blockIdx.x * blockDim.x + threadIdx.x;
    if (n >= NNZ) return;
    atomicAdd(&cntV[Vi[n]], 1);
    atomicAdd(&cntE[Ei[n]], 1);
}

// ------------- exclusive scans for both segment arrays (2 blocks) -----------
__global__ void scan2_kernel(const int* __restrict__ cntE, const int* __restrict__ cntV,
                             int* __restrict__ offE, int* __restrict__ offV,
                             int* __restrict__ curE, int* __restrict__ curV) {
    const int  N   = (blockIdx.x == 0) ? E_EDGES : V_NODES;
    const int* cnt = (blockIdx.x == 0) ? cntE : cntV;
    int* off       = (blockIdx.x == 0) ? offE : offV;
    int* cur       = (blockIdx.x == 0) ? curE : curV;

    __shared__ int tmp[1024];
    __shared__ int sh_carry;
    int t = threadIdx.x;
    if (t == 0) sh_carry = 0;
    __syncthreads();
    for (int base = 0; base < N; base += 1024) {
        int c = sh_carry;
        int i = base + t;
        int v = (i < N) ? cnt[i] : 0;
        tmp[t] = v; __syncthreads();
        for (int st = 1; st < 1024; st <<= 1) {
            int add = (t >= st) ? tmp[t - st] : 0;
            __syncthreads();
            tmp[t] += add;
            __syncthreads();
        }
        if (i < N) { int e = c + tmp[t] - v; off[i] = e; cur[i] = e; }
        __syncthreads();
        if (t == 1023) sh_carry = c + tmp[1023];
        __syncthreads();
    }
}

// ---------------- fill CSR adjacency lists ----------------------------------
__global__ void fill_kernel(const int* __restrict__ Vi, const int* __restrict__ Ei,
                            int* __restrict__ curE, int* __restrict__ curV,
                            int* __restrict__ listE, int* __restrict__ listV) {
    int n = blockIdx.x * blockDim.x + threadIdx.x;
    if (n >= NNZ) return;
    int v = Vi[n], e = Ei[n];
    listE[atomicAdd(&curE[e], 1)] = v;
    listV[atomicAdd(&curV[v], 1)] = e;
}

// ---------------- segmented mean: one wave per destination row --------------
// lane owns 2 columns (float2); k-loop unrolled x4 with independent accums
// so 4 gather loads are in flight per wave.
__global__ void gather_mean(const float* __restrict__ src,
                            float* __restrict__ dst,
                            const int* __restrict__ list,
                            const int* __restrict__ off,
                            const int* __restrict__ cnt,
                            int N) {
    int wid = (blockIdx.x * blockDim.x + threadIdx.x) >> 6;
    if (wid >= N) return;
    int lane = threadIdx.x & 63;
    int o   = off[wid];
    int deg = cnt[wid];
    const float2* s2 = (const float2*)src;

    float2 a0{0.f,0.f}, a1{0.f,0.f}, a2{0.f,0.f}, a3{0.f,0.f};
    int k = 0;
    for (; k + 4 <= deg; k += 4) {
        int i0 = list[o+k];
        int i1 = list[o+k+1];
        int i2 = list[o+k+2];
        int i3 = list[o+k+3];
        float2 v0 = s2[(size_t)i0*64 + lane];
        float2 v1 = s2[(size_t)i1*64 + lane];
        float2 v2 = s2[(size_t)i2*64 + lane];
        float2 v3 = s2[(size_t)i3*64 + lane];
        a0.x += v0.x; a0.y += v0.y;
        a1.x += v1.x; a1.y += v1.y;
        a2.x += v2.x; a2.y += v2.y;
        a3.x += v3.x; a3.y += v3.y;
    }
    for (; k < deg; ++k) {
        int i0 = list[o+k];
        float2 v0 = s2[(size_t)i0*64 + lane];
        a0.x += v0.x; a0.y += v0.y;
    }
    float inv = 1.0f / fmaxf((float)deg, 1.0f);
    float2 r;
    r.x = (a0.x + a1.x + a2.x + a3.x) * inv;
    r.y = (a0.y + a1.y + a2.y + a3.y) * inv;
    ((float2*)dst)[(size_t)wid*64 + lane] = r;
}

// -------- read-only stats pass: entropy / colsum / gram over M --------------
__global__ void stats_kernel(const float* __restrict__ M, int N,
                             float* __restrict__ stats) {
    int t = threadIdx.x;
    int r0 = t >> 7;         // row-in-pair (0/1)
    int d = t & 127;         // column
    int s = d >> 4;          // subspace
    int i = d & 15;          // index within subspace

    float ent = 0.f, col = 0.f;
    float gram[16];
    #pragma unroll
    for (int j = 0; j < 16; ++j) gram[j] = 0.f;

    for (int row = blockIdx.x * 2 + r0; row < N; row += gridDim.x * 2) {
        float y = M[(size_t)row * DD + d];
        ent -= y * logf(y + EPSF);
        col += y;
        #pragma unroll
        for (int j = 0; j < 16; ++j) {
            float yj = __shfl(y, j, 16);   // broadcast within 16-lane group
            gram[j] += y * yj;
        }
    }

    __shared__ float red[256];
    red[t] = ent; __syncthreads();
    for (int st = 128; st > 0; st >>= 1) {
        if (t < st) red[t] += red[t + st];
        __syncthreads();
    }
    if (t == 0) atomicAdd(&stats[0], red[0]);
    __syncthreads();
    red[t] = col; __syncthreads();
    if (t < 128) atomicAdd(&stats[1 + d], red[t] + red[t + 128]);
    __syncthreads();
    for (int j = 0; j < 16; ++j) {
        red[t] = gram[j]; __syncthreads();
        if (t < 128) atomicAdd(&stats[129 + s * 256 + i * 16 + j], red[t] + red[t + 128]);
        __syncthreads();
    }
}

// ---------------- final loss from the 8 stats blocks ------------------------
__global__ void loss_kernel(const float* __restrict__ stats, float* __restrict__ out) {
    int t = threadIdx.x;
    float acc_l = 0.f, acc_g = 0.f;

    if (t < 8) {
        float N = (t & 1) ? (float)V_NODES : (float)E_EDGES;
        acc_l = stats[t * STATS_STRIDE] / (N * (float)S_SUB);
    }

    for (int u = t; u < 8 * 128; u += blockDim.x) {
        int side = u >> 7, d = u & 127;
        float N = (side & 1) ? (float)V_NODES : (float)E_EDGES;
        float p = stats[side * STATS_STRIDE + 1 + d] / N;
        acc_g += p * logf(p + EPSF) / (float)S_SUB;
    }

    for (int u = t; u < 8 * 8 * 16; u += blockDim.x) {
        int side = u >> 7;
        int s = (u >> 4) & 7;
        int i = u & 15;
        const float* G = stats + side * STATS_STRIDE + 129 + s * 256;
        float nii = sqrtf(G[i * 16 + i]);
        float C[16];
        float m = -INFINITY;
        #pragma unroll
        for (int j = 0; j < 16; ++j) {
            float njj = sqrtf(G[j * 16 + j]);
            float c = G[i * 16 + j] / fmaxf(nii * njj, EPSF);
            C[j] = c;
            m = fmaxf(m, c);
        }
        float sum = 0.f;
        #pragma unroll
        for (int j = 0; j < 16; ++j) sum += expf(C[j] - m);
        float lse = logf(sum) + m;
        acc_g += (lse - C[i]) / (float)(S_SUB * K_SUB);
    }

    __shared__ float redl[256], redg[256];
    redl[t] = acc_l; redg[t] = acc_g; __syncthreads();
    for (int st = 128; st > 0; st >>= 1) {
        if (t < st) { redl[t] += redl[t + st]; redg[t] += redg[t + st]; }
        __syncthreads();
    }
    if (t == 0) { out[0] = redl[0]; out[1] = redg[0]; }
}

extern "C" void kernel_launch(void* const* d_in, const int* in_sizes, int n_in,
                              void* d_out, int out_size, void* d_ws, size_t ws_size,
                              hipStream_t stream) {
    const float* emb = (const float*)d_in[0];
    const float* gum = (const float*)d_in[1];
    const int*   Vi  = (const int*)d_in[2];
    const int*   Ei  = (const int*)d_in[3];
    float* out = (float*)d_out;

    char* ws = (char*)d_ws;
    size_t off = 0;
    float* X = (float*)(ws + off);      off += (size_t)V_NODES * DD * 4;   // 25.6 MB
    float* Y = (float*)(ws + off);      off += (size_t)E_EDGES * DD * 4;   // 12.8 MB
    int* listE = (int*)(ws + off);      off += (size_t)NNZ * 4;            // 2.4 MB
    int* listV = (int*)(ws + off);      off += (size_t)NNZ * 4;            // 2.4 MB
    int* cntE  = (int*)(ws + off);      off += (size_t)E_EDGES * 4;
    int* cntV  = (int*)(ws + off);      off += (size_t)V_NODES * 4;
    int* offE  = (int*)(ws + off);      off += (size_t)E_EDGES * 4;
    int* offV  = (int*)(ws + off);      off += (size_t)V_NODES * 4;
    int* curE  = (int*)(ws + off);      off += (size_t)E_EDGES * 4;
    int* curV  = (int*)(ws + off);      off += (size_t)V_NODES * 4;
    float* stats = (float*)(ws + off);  off += (size_t)8 * STATS_STRIDE * 4;

    // zero counts + stats every launch (deterministic state)
    hipMemsetAsync(cntE, 0, ((size_t)E_EDGES + V_NODES) * 4, stream);
    hipMemsetAsync(stats, 0, (size_t)8 * STATS_STRIDE * 4, stream);

    softmax16_kernel<<<(V_NODES * DD + 255) / 256, 256, 0, stream>>>(emb, gum, X);
    hist_kernel<<<(NNZ + 255) / 256, 256, 0, stream>>>(Vi, Ei, cntV, cntE);
    scan2_kernel<<<2, 1024, 0, stream>>>(cntE, cntV, offE, offV, curE, curV);
    fill_kernel<<<(NNZ + 255) / 256, 256, 0, stream>>>(Vi, Ei, curE, curV, listE, listV);

    const int SB = 256;   // stats grid
    for (int step = 0; step < NUM_STEP; ++step) {
        // Y = scatter_mean(X[Vi], Ei): one wave per edge row
        gather_mean<<<(E_EDGES * 64 + 255) / 256, 256, 0, stream>>>(X, Y, listE, offE, cntE, E_EDGES);
        stats_kernel<<<SB, 256, 0, stream>>>(Y, E_EDGES, stats + (2 * step) * STATS_STRIDE);
        // X = scatter_mean(Y[Ei], Vi): one wave per node row
        gather_mean<<<(V_NODES * 64 + 255) / 256, 256, 0, stream>>>(Y, X, listV, offV, cntV, V_NODES);
        stats_kernel<<<SB, 256, 0, stream>>>(X, V_NODES, stats + (2 * step + 1) * STATS_STRIDE);
    }

    loss_kernel<<<1, 256, 0, stream>>>(stats, out);
}